// Round 7
// baseline (692.699 us; speedup 1.0000x reference)
//
#include <hip/hip_runtime.h>

// N=65536, D_IN=1024, D_LAT=128, K=512
#define NROWS 65536
#define DIN   1024
#define DLAT  128
#define KC    512

typedef __attribute__((ext_vector_type(8))) short bf16x8;
typedef __attribute__((ext_vector_type(4))) float f32x4;

// direct global->LDS DMA, 16B per lane, LDS dest = wave-uniform base + lane*16
#define GLDS16(gp, lp)                                                          \
    __builtin_amdgcn_global_load_lds((const __attribute__((address_space(1))) void*)(gp), \
                                     (__attribute__((address_space(3))) void*)(lp), 16, 0, 0)

__device__ inline short f2bf(float f) {
    unsigned u = __float_as_uint(f);
    return (short)((u + 0x7FFFu + ((u >> 16) & 1u)) >> 16);  // RNE f32->bf16
}

#define MFMA __builtin_amdgcn_mfma_f32_16x16x32_bf16

// ---------- prep: Wt[n][k] = bf16(W[k][n]); cb = bf16(centroids) ----------
__global__ __launch_bounds__(256) void prep_convert(const float* __restrict__ W,
                                                    const float* __restrict__ C,
                                                    short* __restrict__ Wt,
                                                    short* __restrict__ cb) {
    int idx = blockIdx.x * 256 + threadIdx.x;
    if (idx < DLAT * DIN) {                 // Wt[n][k] = W[k][n]
        int n = idx >> 10, k = idx & 1023;
        Wt[idx] = f2bf(W[k * DLAT + n]);
    } else {
        int i2 = idx - DLAT * DIN;
        if (i2 < KC * DLAT) cb[i2] = f2bf(C[i2]);
    }
}

// ---------- prep: csq[k] = ||centroid_k||^2 ----------
__global__ __launch_bounds__(64) void prep_csq(const float* __restrict__ C,
                                               float* __restrict__ csq) {
    int row = blockIdx.x;
    int lane = threadIdx.x;
    float a = C[row * DLAT + lane];
    float b = C[row * DLAT + 64 + lane];
    float s = a * a + b * b;
    #pragma unroll
    for (int m = 32; m >= 1; m >>= 1) s += __shfl_xor(s, m, 64);
    if (lane == 0) csq[row] = s;
}

// ---------- FUSED: l = x@W+b -> Q -> Fq partials ----------
// Phase 1: BK=128, x-only LDS dbuf (2x32KB, 512B/row granule), W frags direct from L1/L2.
// Phase 2: two-pass (rowsum, then recompute+emit) with per-wave 16KB LDS transpose
//          buffers so l/Q global writes are row-contiguous (512B granule).
__global__ __launch_bounds__(256, 2) void fused2(const float* __restrict__ x,
                                                 const short* __restrict__ Wt,
                                                 const float* __restrict__ bias,
                                                 const short* __restrict__ cb,
                                                 const float* __restrict__ csq,
                                                 float* __restrict__ lout,
                                                 float* __restrict__ Qout,
                                                 float* __restrict__ partial) {
    __shared__ char lds[65536];
    const int t = threadIdx.x;
    const int wid = t >> 6, lane = t & 63;
    const int l16 = lane & 15, lhi = lane >> 4;
    const int row0 = blockIdx.x * 64;
    const int arow = wid * 16 + l16;

    // ---- phase 1 ----
    // x chunk = 64 rows x 128 f32 (512B row = 32 x 16B slots). Granule g=j*256+t:
    // row=g>>5, slot=g&31; global src slot = slot ^ (row&15) (read-side uses same XOR).
    const int xrow_ = t >> 5, xslot = t & 31;

    f32x4 acc[8];
    #pragma unroll
    for (int i = 0; i < 8; ++i) acc[i] = (f32x4){0.f, 0.f, 0.f, 0.f};

    #define XSTAGE(k, buf) {                                                         \
        char* xb = lds + (buf) * 32768;                                              \
        _Pragma("unroll")                                                            \
        for (int j = 0; j < 8; ++j) {                                                \
            const int row = j * 8 + xrow_;                                           \
            GLDS16(x + (long)(row0 + row) * DIN + (k) * 128 + ((xslot ^ (row & 15)) << 2), \
                   xb + (j * 256 + t) * 16);                                         \
        } }

    XSTAGE(0, 0);
    __syncthreads();

    for (int kc = 0; kc < 8; ++kc) {
        if (kc < 7) XSTAGE(kc + 1, (kc + 1) & 1);
        const float* xs = (const float*)(lds + (kc & 1) * 32768);
        #pragma unroll
        for (int ks = 0; ks < 4; ++ks) {
            const int s0 = ks * 8 + lhi * 2;
            const float4 va0 = *(const float4*)(xs + arow * 128 + (((s0    ) ^ l16) << 2));
            const float4 va1 = *(const float4*)(xs + arow * 128 + (((s0 + 1) ^ l16) << 2));
            bf16x8 af;
            af[0] = f2bf(va0.x); af[1] = f2bf(va0.y); af[2] = f2bf(va0.z); af[3] = f2bf(va0.w);
            af[4] = f2bf(va1.x); af[5] = f2bf(va1.y); af[6] = f2bf(va1.z); af[7] = f2bf(va1.w);
            #pragma unroll
            for (int nb = 0; nb < 8; ++nb) {
                const bf16x8 bf = *(const bf16x8*)(Wt + (long)(nb * 16 + l16) * DIN
                                                   + kc * 128 + ks * 32 + lhi * 8);
                acc[nb] = MFMA(af, bf, acc[nb], 0, 0, 0);
            }
        }
        __syncthreads();
    }
    #undef XSTAGE

    // ---- phase 1.5: bias; l -> swizzled LDS (own-wave rows); contiguous l write ----
    float* l_lds = (float*)lds;   // 64 rows x 128 f32, slot-swizzled (overlays buf0)
    #pragma unroll
    for (int nb = 0; nb < 8; ++nb) {
        const int col = nb * 16 + l16;
        const float bv = bias[col];
        const int slot = col >> 2, e = col & 3;
        #pragma unroll
        for (int r = 0; r < 4; ++r) {
            const int row = wid * 16 + lhi * 4 + r;   // C/D: col=lane&15, row=(lane>>4)*4+r
            l_lds[row * 128 + ((slot ^ (row & 15)) << 2) + e] = acc[nb][r] + bv;
        }
    }
    const int rsub = lane >> 5, c4l = lane & 31;
    #pragma unroll
    for (int it = 0; it < 8; ++it) {   // own rows -> 512B contiguous stores
        const int row = wid * 16 + it * 2 + rsub;
        const float4 v = *(const float4*)(l_lds + row * 128 + ((c4l ^ (row & 15)) << 2));
        *(float4*)(lout + (long)(row0 + row) * DLAT + c4l * 4) = v;
    }

    // ---- phase 2: A-frags + ||l||^2 ----
    bf16x8 af2[4];
    float sq = 0.f;
    #pragma unroll
    for (int ks = 0; ks < 4; ++ks) {
        const int s0 = ks * 8 + lhi * 2;
        const float4 v0 = *(const float4*)(l_lds + arow * 128 + (((s0    ) ^ l16) << 2));
        const float4 v1 = *(const float4*)(l_lds + arow * 128 + (((s0 + 1) ^ l16) << 2));
        sq += v0.x * v0.x + v0.y * v0.y + v0.z * v0.z + v0.w * v0.w
            + v1.x * v1.x + v1.y * v1.y + v1.z * v1.z + v1.w * v1.w;
        bf16x8 a;
        a[0] = f2bf(v0.x); a[1] = f2bf(v0.y); a[2] = f2bf(v0.z); a[3] = f2bf(v0.w);
        a[4] = f2bf(v1.x); a[5] = f2bf(v1.y); a[6] = f2bf(v1.z); a[7] = f2bf(v1.w);
        af2[ks] = a;
    }
    sq += __shfl_xor(sq, 16, 64);
    sq += __shfl_xor(sq, 32, 64);
    float lsqr[4];
    #pragma unroll
    for (int r = 0; r < 4; ++r) lsqr[r] = __shfl(sq, lhi * 4 + r, 64);

    // pass A: row sums of nm only (nothing kept)
    float rsum[4] = {0.f, 0.f, 0.f, 0.f};
    #pragma unroll
    for (int nb = 0; nb < 32; ++nb) {
        f32x4 s2 = (f32x4){0.f, 0.f, 0.f, 0.f};
        const short* cbase = cb + (nb * 16 + l16) * DLAT;
        #pragma unroll
        for (int ks = 0; ks < 4; ++ks)
            s2 = MFMA(af2[ks], *(const bf16x8*)(cbase + ks * 32 + lhi * 8), s2, 0, 0, 0);
        const float cs = csq[nb * 16 + l16];
        #pragma unroll
        for (int r = 0; r < 4; ++r)
            rsum[r] += 1.f / (1.f + lsqr[r] + cs - 2.f * s2[r]);
    }
    #pragma unroll
    for (int m = 1; m <= 8; m <<= 1) {
        #pragma unroll
        for (int r = 0; r < 4; ++r) rsum[r] += __shfl_xor(rsum[r], m, 64);
    }
    float inv[4];
    #pragma unroll
    for (int r = 0; r < 4; ++r) inv[r] = 1.f / rsum[r];

    __syncthreads();   // everyone done with l_lds (af2 built) before wbuf overwrites it

    // pass B: recompute nm, emit Q through per-wave transpose buffer (2 halves x 8 rows)
    float* wbuf = (float*)(lds + wid * 16384);   // 8 rows x 512 f32 = 16KB per wave
    float cp4[4] = {0.f, 0.f, 0.f, 0.f};
    #pragma unroll
    for (int h = 0; h < 2; ++h) {
        #pragma unroll
        for (int nb = 0; nb < 32; ++nb) {
            f32x4 s2 = (f32x4){0.f, 0.f, 0.f, 0.f};
            const short* cbase = cb + (nb * 16 + l16) * DLAT;
            #pragma unroll
            for (int ks = 0; ks < 4; ++ks)
                s2 = MFMA(af2[ks], *(const bf16x8*)(cbase + ks * 32 + lhi * 8), s2, 0, 0, 0);
            const float cs = csq[nb * 16 + l16];
            if ((lhi >> 1) == h) {
                const int lr0 = (lhi & 1) * 4;
                #pragma unroll
                for (int r = 0; r < 4; ++r) {
                    float nm = 1.f / (1.f + lsqr[r] + cs - 2.f * s2[r]);
                    wbuf[(lr0 + r) * 512 + nb * 16 + l16] = nm * inv[r];
                }
            }
        }
        #pragma unroll
        for (int it = 0; it < 4; ++it) {       // contiguous 512B-per-row Q stores
            const int lr = it * 2 + rsub;
            const float4 v = *(const float4*)(wbuf + lr * 512 + c4l * 4);
            *(float4*)(Qout + (long)(row0 + wid * 16 + h * 8 + lr) * KC + c4l * 4) = v;
            cp4[0] += v.x; cp4[1] += v.y; cp4[2] += v.z; cp4[3] += v.w;
        }
    }
    // combine row-parity partners -> per-wave colsum of its 16 rows
    #pragma unroll
    for (int i = 0; i < 4; ++i) cp4[i] += __shfl_xor(cp4[i], 32, 64);

    __syncthreads();                      // wbufs dead; reuse lds head for Fq exchange
    float* lds_fq = (float*)lds;          // [4][KC] = 8KB
    if (lane < 32) {
        float4 v = {cp4[0], cp4[1], cp4[2], cp4[3]};
        *(float4*)(lds_fq + wid * KC + c4l * 4) = v;
    }
    __syncthreads();
    for (int c = t; c < KC; c += 256) {
        partial[(long)blockIdx.x * KC + c] =
            lds_fq[0 * KC + c] + lds_fq[1 * KC + c] + lds_fq[2 * KC + c] + lds_fq[3 * KC + c];
    }
}

// ---------- Fq reduce: fqinv[c] = 1 / sum over 1024 block partials ----------
__global__ __launch_bounds__(256) void fq_reduce(const float* __restrict__ partial,
                                                 float* __restrict__ fqinv) {
    int c = blockIdx.x;
    float s = 0.f;
    #pragma unroll
    for (int i = 0; i < 4; ++i) s += partial[(long)(threadIdx.x + i * 256) * KC + c];
    __shared__ float red[256];
    red[threadIdx.x] = s;
    __syncthreads();
    for (int off = 128; off >= 1; off >>= 1) {
        if (threadIdx.x < off) red[threadIdx.x] += red[threadIdx.x + off];
        __syncthreads();
    }
    if (threadIdx.x == 0) fqinv[c] = 1.f / red[0];
}

// ---------- P pass: stage l tile contiguously, recompute nm, transpose-write P ----------
// P = u / rowsum(u), u = nm^2 / Fq  (row-scale invariant, never re-reads Q)
__global__ __launch_bounds__(256, 2) void p2(const float* __restrict__ lout,
                                             const short* __restrict__ cb,
                                             const float* __restrict__ csq,
                                             const float* __restrict__ fqinv,
                                             float* __restrict__ P) {
    __shared__ char lds[65536];
    const int t = threadIdx.x;
    const int wid = t >> 6, lane = t & 63;
    const int l16 = lane & 15, lhi = lane >> 4;
    const int row0 = blockIdx.x * 64;
    const int arow = wid * 16 + l16;
    const int xrow_ = t >> 5, xslot = t & 31;

    // stage l tile (64 x 128 f32 = 32KB, contiguous 512B per row) with read-side XOR
    #pragma unroll
    for (int j = 0; j < 8; ++j) {
        const int row = j * 8 + xrow_;
        GLDS16(lout + (long)(row0 + row) * DLAT + ((xslot ^ (row & 15)) << 2),
               lds + (j * 256 + t) * 16);
    }
    __syncthreads();

    float* l_lds = (float*)lds;
    bf16x8 af2[4];
    float sq = 0.f;
    #pragma unroll
    for (int ks = 0; ks < 4; ++ks) {
        const int s0 = ks * 8 + lhi * 2;
        const float4 v0 = *(const float4*)(l_lds + arow * 128 + (((s0    ) ^ l16) << 2));
        const float4 v1 = *(const float4*)(l_lds + arow * 128 + (((s0 + 1) ^ l16) << 2));
        sq += v0.x * v0.x + v0.y * v0.y + v0.z * v0.z + v0.w * v0.w
            + v1.x * v1.x + v1.y * v1.y + v1.z * v1.z + v1.w * v1.w;
        bf16x8 a;
        a[0] = f2bf(v0.x); a[1] = f2bf(v0.y); a[2] = f2bf(v0.z); a[3] = f2bf(v0.w);
        a[4] = f2bf(v1.x); a[5] = f2bf(v1.y); a[6] = f2bf(v1.z); a[7] = f2bf(v1.w);
        af2[ks] = a;
    }
    sq += __shfl_xor(sq, 16, 64);
    sq += __shfl_xor(sq, 32, 64);
    float lsqr[4];
    #pragma unroll
    for (int r = 0; r < 4; ++r) lsqr[r] = __shfl(sq, lhi * 4 + r, 64);

    // pass A: rowsum of u
    float rsum[4] = {0.f, 0.f, 0.f, 0.f};
    #pragma unroll
    for (int nb = 0; nb < 32; ++nb) {
        f32x4 s2 = (f32x4){0.f, 0.f, 0.f, 0.f};
        const short* cbase = cb + (nb * 16 + l16) * DLAT;
        #pragma unroll
        for (int ks = 0; ks < 4; ++ks)
            s2 = MFMA(af2[ks], *(const bf16x8*)(cbase + ks * 32 + lhi * 8), s2, 0, 0, 0);
        const float cs = csq[nb * 16 + l16];
        const float fqi = fqinv[nb * 16 + l16];
        #pragma unroll
        for (int r = 0; r < 4; ++r) {
            float nm = 1.f / (1.f + lsqr[r] + cs - 2.f * s2[r]);
            rsum[r] += nm * nm * fqi;
        }
    }
    #pragma unroll
    for (int m = 1; m <= 8; m <<= 1) {
        #pragma unroll
        for (int r = 0; r < 4; ++r) rsum[r] += __shfl_xor(rsum[r], m, 64);
    }
    float inv[4];
    #pragma unroll
    for (int r = 0; r < 4; ++r) inv[r] = 1.f / rsum[r];

    __syncthreads();   // all waves done reading l_lds before wbuf overlays

    float* wbuf = (float*)(lds + wid * 16384);
    const int rsub = lane >> 5, c4l = lane & 31;
    #pragma unroll
    for (int h = 0; h < 2; ++h) {
        #pragma unroll
        for (int nb = 0; nb < 32; ++nb) {
            f32x4 s2 = (f32x4){0.f, 0.f, 0.f, 0.f};
            const short* cbase = cb + (nb * 16 + l16) * DLAT;
            #pragma unroll
            for (int ks = 0; ks < 4; ++ks)
                s2 = MFMA(af2[ks], *(const bf16x8*)(cbase + ks * 32 + lhi * 8), s2, 0, 0, 0);
            const float cs = csq[nb * 16 + l16];
            const float fqi = fqinv[nb * 16 + l16];
            if ((lhi >> 1) == h) {
                const int lr0 = (lhi & 1) * 4;
                #pragma unroll
                for (int r = 0; r < 4; ++r) {
                    float nm = 1.f / (1.f + lsqr[r] + cs - 2.f * s2[r]);
                    wbuf[(lr0 + r) * 512 + nb * 16 + l16] = nm * nm * fqi * inv[r];
                }
            }
        }
        #pragma unroll
        for (int it = 0; it < 4; ++it) {
            const int lr = it * 2 + rsub;
            const float4 v = *(const float4*)(wbuf + lr * 512 + c4l * 4);
            *(float4*)(P + (long)(row0 + wid * 16 + h * 8 + lr) * KC + c4l * 4) = v;
        }
    }
}

extern "C" void kernel_launch(void* const* d_in, const int* in_sizes, int n_in,
                              void* d_out, int out_size, void* d_ws, size_t ws_size,
                              hipStream_t stream) {
    const float* x  = (const float*)d_in[0];
    const float* W  = (const float*)d_in[1];
    const float* b  = (const float*)d_in[2];
    const float* C  = (const float*)d_in[3];

    float* out  = (float*)d_out;
    float* lout = out;                                   // 65536*128
    float* Qout = out + (long)NROWS * DLAT;              // 65536*512
    float* Pout = Qout + (long)NROWS * KC;               // 65536*512

    // workspace layout (~2.44 MB)
    char*  ws      = (char*)d_ws;
    short* Wt      = (short*)ws;                         // 131072 * 2 B
    short* cb      = (short*)(ws + 262144);              // 65536 * 2 B
    float* csq     = (float*)(ws + 262144 + 131072);     // 512 * 4 B
    float* partial = (float*)(ws + 395264);              // 1024*512*4 = 2 MB
    float* fqinv   = (float*)(ws + 395264 + 2097152);    // 512 * 4 B

    hipLaunchKernelGGL(prep_convert, dim3(768),  dim3(256), 0, stream, W, C, Wt, cb);
    hipLaunchKernelGGL(prep_csq,     dim3(512),  dim3(64),  0, stream, C, csq);
    hipLaunchKernelGGL(fused2,       dim3(1024), dim3(256), 0, stream,
                       x, Wt, b, cb, csq, lout, Qout, partial);
    hipLaunchKernelGGL(fq_reduce,    dim3(512),  dim3(256), 0, stream, partial, fqinv);
    hipLaunchKernelGGL(p2,           dim3(1024), dim3(256), 0, stream,
                       lout, cb, csq, fqinv, Pout);
}

// Round 8
// 254.823 us; speedup vs baseline: 2.7183x; 2.7183x over previous
//
#include <hip/hip_runtime.h>

// N=65536, D_IN=1024, D_LAT=128, K=512
#define NROWS 65536
#define DIN   1024
#define DLAT  128
#define KC    512

typedef __attribute__((ext_vector_type(8))) short bf16x8;
typedef __attribute__((ext_vector_type(4))) float f32x4;

// direct global->LDS DMA, 16B per lane, LDS dest = wave-uniform base + lane*16
#define GLDS16(gp, lp)                                                          \
    __builtin_amdgcn_global_load_lds((const __attribute__((address_space(1))) void*)(gp), \
                                     (__attribute__((address_space(3))) void*)(lp), 16, 0, 0)

__device__ inline short f2bf(float f) {
    unsigned u = __float_as_uint(f);
    return (short)((u + 0x7FFFu + ((u >> 16) & 1u)) >> 16);  // RNE f32->bf16
}

#define MFMA __builtin_amdgcn_mfma_f32_16x16x32_bf16

// ---------- prep: Wt[n][k] = bf16(W[k][n]); cb = bf16(centroids) ----------
__global__ __launch_bounds__(256) void prep_convert(const float* __restrict__ W,
                                                    const float* __restrict__ C,
                                                    short* __restrict__ Wt,
                                                    short* __restrict__ cb) {
    int idx = blockIdx.x * 256 + threadIdx.x;
    if (idx < DLAT * DIN) {                 // Wt[n][k] = W[k][n]
        int n = idx >> 10, k = idx & 1023;
        Wt[idx] = f2bf(W[k * DLAT + n]);
    } else {
        int i2 = idx - DLAT * DIN;
        if (i2 < KC * DLAT) cb[i2] = f2bf(C[i2]);
    }
}

// ---------- prep: csq[k] = ||centroid_k||^2 ----------
__global__ __launch_bounds__(64) void prep_csq(const float* __restrict__ C,
                                               float* __restrict__ csq) {
    int row = blockIdx.x;
    int lane = threadIdx.x;
    float a = C[row * DLAT + lane];
    float b = C[row * DLAT + 64 + lane];
    float s = a * a + b * b;
    #pragma unroll
    for (int m = 32; m >= 1; m >>= 1) s += __shfl_xor(s, m, 64);
    if (lane == 0) csq[row] = s;
}

// ---------- K1: l = x @ W + b  — SEQUENTIAL-STREAM structure ----------
// 32 rows/block (2048 blocks). The block's x-span (32 rows x 4KB = 128KB) is read
// front-to-back in lane-adjacent 32B granules (DRAM page-friendly), converted to
// bf16, and XOR-swizzled into a fully-resident 64KB LDS tile (full K -> x touched
// exactly once, no K-chunk re-walk). W is GLDS-staged per BK=64 chunk (16KB, L2-hot,
// large granule — NEVER per-lane scattered, r7 lesson). LDS 80KB -> 2 blocks/CU:
// one block's MFMA/W-stage phase fills the other's stream stalls.
__global__ __launch_bounds__(256) void gemm_l(const float* __restrict__ x,
                                              const short* __restrict__ Wt,
                                              const float* __restrict__ bias,
                                              float* __restrict__ lout) {
    __shared__ char lds[81920];
    short* xls = (short*)lds;            // [32 rows][1024] bf16, slot^=(row&7) swizzle
    short* wls = (short*)(lds + 65536);  // [128 n][64] bf16,  slot^=(n&7)  swizzle

    const int t = threadIdx.x;
    const int lane = t & 63, wid = t >> 6;
    const int l16 = lane & 15, lhi = lane >> 4;
    const int row0 = blockIdx.x * 32;
    const int rg = wid & 1;        // row-group: rows rg*16..+15
    const int nbh = wid >> 1;      // nb-half:   nb = nbh*4..+3

    // ---- stream x sequentially: 16 steps, 32B (8 f32) per thread-step ----
    float4 v0[16], v1[16];
    const float* xb = x + (long)row0 * DIN;
    #pragma unroll
    for (int s = 0; s < 16; ++s) {
        const float* p = xb + (long)(s * 256 + t) * 8;   // lane-adjacent 32B granules
        v0[s] = *(const float4*)p;
        v1[s] = *(const float4*)(p + 4);
    }

    // stage W chunk 0 while x loads are in flight
    #define WSTAGE(kc) { _Pragma("unroll")                                        \
        for (int j = 0; j < 4; ++j) {                                             \
            const int g2 = j * 256 + t;                                           \
            const int n = g2 >> 3, s2 = g2 & 7;                                   \
            GLDS16(Wt + (long)n * DIN + (kc) * 64 + ((s2 ^ (n & 7)) << 3),        \
                   (char*)wls + g2 * 16);                                         \
        } }
    WSTAGE(0);

    // convert + swizzled ds_write (compiler inserts staggered vmcnt per use)
    #pragma unroll
    for (int s = 0; s < 16; ++s) {
        const int g = s * 256 + t;
        const int row = g >> 7, c32 = g & 127;   // 128 x 32B units per 4KB row
        bf16x8 o;
        o[0] = f2bf(v0[s].x); o[1] = f2bf(v0[s].y); o[2] = f2bf(v0[s].z); o[3] = f2bf(v0[s].w);
        o[4] = f2bf(v1[s].x); o[5] = f2bf(v1[s].y); o[6] = f2bf(v1[s].z); o[7] = f2bf(v1[s].w);
        *(bf16x8*)(xls + row * 1024 + ((c32 ^ (row & 7)) << 3)) = o;
    }

    f32x4 acc[4];
    #pragma unroll
    for (int i = 0; i < 4; ++i) acc[i] = (f32x4){0.f, 0.f, 0.f, 0.f};

    const int arow = rg * 16 + l16;
    __syncthreads();   // drains ds_writes (lgkm) + W GLDS (vm): x tile + W chunk 0 ready

    for (int kc = 0; kc < 16; ++kc) {
        #pragma unroll
        for (int ks2 = 0; ks2 < 2; ++ks2) {
            const int ks = kc * 2 + ks2;
            const bf16x8 af = *(const bf16x8*)(xls + arow * 1024
                                               + (((ks * 4 + lhi) ^ (arow & 7)) << 3));
            #pragma unroll
            for (int nb = 0; nb < 4; ++nb) {
                const int n = (nbh * 4 + nb) * 16 + l16;
                const bf16x8 bf = *(const bf16x8*)(wls + n * 64
                                                   + (((ks2 * 4 + lhi) ^ (n & 7)) << 3));
                acc[nb] = MFMA(af, bf, acc[nb], 0, 0, 0);
            }
        }
        if (kc < 15) {
            __syncthreads();     // all waves done reading W buffer
            WSTAGE(kc + 1);
            __syncthreads();     // W chunk kc+1 landed (vm drain at barrier)
        }
    }
    #undef WSTAGE

    #pragma unroll
    for (int nb = 0; nb < 4; ++nb) {
        const int col = (nbh * 4 + nb) * 16 + l16;
        const float bv = bias[col];
        #pragma unroll
        for (int r = 0; r < 4; ++r) {
            const int row = rg * 16 + lhi * 4 + r;   // C/D: col=lane&15, row=(lane>>4)*4+reg
            lout[(long)(row0 + row) * DLAT + col] = acc[nb][r] + bv;
        }
    }
}

// ---------- K2: S = l @ c^T; D; num=1/(1+D); Q=num/rowsum; Fq partials ----------
__global__ __launch_bounds__(256, 1) void gemm2_q(const float* __restrict__ lout,
                                                  const short* __restrict__ cb,
                                                  const float* __restrict__ csq,
                                                  float* __restrict__ Qout,
                                                  float* __restrict__ partial) {
    const int wid = threadIdx.x >> 6, lane = threadIdx.x & 63;
    const int l16 = lane & 15, lhi = lane >> 4;
    const int row0 = blockIdx.x * 64 + wid * 16;

    bf16x8 af[4];
    float sq = 0.f;
    const float* lrow = lout + (long)(row0 + l16) * DLAT;
    #pragma unroll
    for (int ks = 0; ks < 4; ++ks) {
        const float4* lp = (const float4*)(lrow + ks * 32 + lhi * 8);
        float4 v0 = lp[0], v1 = lp[1];
        sq += v0.x * v0.x + v0.y * v0.y + v0.z * v0.z + v0.w * v0.w
            + v1.x * v1.x + v1.y * v1.y + v1.z * v1.z + v1.w * v1.w;
        bf16x8 a;
        a[0] = f2bf(v0.x); a[1] = f2bf(v0.y); a[2] = f2bf(v0.z); a[3] = f2bf(v0.w);
        a[4] = f2bf(v1.x); a[5] = f2bf(v1.y); a[6] = f2bf(v1.z); a[7] = f2bf(v1.w);
        af[ks] = a;
    }
    sq += __shfl_xor(sq, 16, 64);
    sq += __shfl_xor(sq, 32, 64);          // lane L holds lsq of row (L&15)
    float lsqr[4];
    #pragma unroll
    for (int r = 0; r < 4; ++r) lsqr[r] = __shfl(sq, lhi * 4 + r, 64);

    f32x4 numv[32];
    float rsum[4] = {0.f, 0.f, 0.f, 0.f};
    #pragma unroll
    for (int nb = 0; nb < 32; ++nb) {
        f32x4 acc = (f32x4){0.f, 0.f, 0.f, 0.f};
        const short* cbase = cb + (nb * 16 + l16) * DLAT;
        #pragma unroll
        for (int ks = 0; ks < 4; ++ks) {
            const bf16x8 bf = *(const bf16x8*)(cbase + ks * 32 + lhi * 8);
            acc = MFMA(af[ks], bf, acc, 0, 0, 0);
        }
        float cs = csq[nb * 16 + l16];
        f32x4 nm;
        #pragma unroll
        for (int r = 0; r < 4; ++r) {
            float Dv = lsqr[r] + cs - 2.f * acc[r];
            float v = 1.f / (1.f + Dv);    // alpha=1: (1+D)^(-1)
            nm[r] = v;
            rsum[r] += v;
        }
        numv[nb] = nm;
    }
    #pragma unroll
    for (int m = 1; m <= 8; m <<= 1) {
        #pragma unroll
        for (int r = 0; r < 4; ++r) rsum[r] += __shfl_xor(rsum[r], m, 64);
    }
    float inv[4];
    #pragma unroll
    for (int r = 0; r < 4; ++r) inv[r] = 1.f / rsum[r];

    __shared__ float lds_fq[4][KC];
    #pragma unroll
    for (int nb = 0; nb < 32; ++nb) {
        float cp = 0.f;
        #pragma unroll
        for (int r = 0; r < 4; ++r) {
            float q = numv[nb][r] * inv[r];
            Qout[(long)(row0 + lhi * 4 + r) * KC + nb * 16 + l16] = q;
            cp += q;
        }
        cp += __shfl_xor(cp, 16, 64);
        cp += __shfl_xor(cp, 32, 64);      // colsum over this wave's 16 rows
        if (lhi == 0) lds_fq[wid][nb * 16 + l16] = cp;
    }
    __syncthreads();
    for (int c = threadIdx.x; c < KC; c += 256) {
        partial[(long)blockIdx.x * KC + c] =
            lds_fq[0][c] + lds_fq[1][c] + lds_fq[2][c] + lds_fq[3][c];
    }
}

// ---------- K3: Fq[c] = sum over 1024 block partials (deterministic tree) ----------
__global__ __launch_bounds__(256) void fq_reduce(const float* __restrict__ partial,
                                                 float* __restrict__ fq) {
    int c = blockIdx.x;
    float s = 0.f;
    #pragma unroll
    for (int i = 0; i < 4; ++i) s += partial[(long)(threadIdx.x + i * 256) * KC + c];
    __shared__ float red[256];
    red[threadIdx.x] = s;
    __syncthreads();
    for (int off = 128; off >= 1; off >>= 1) {
        if (threadIdx.x < off) red[threadIdx.x] += red[threadIdx.x + off];
        __syncthreads();
    }
    if (threadIdx.x == 0) fq[c] = red[0];
}

// ---------- K4: P = rownorm(Q^2 / Fq) ----------
__global__ __launch_bounds__(256) void p_kernel(const float* __restrict__ Q,
                                                const float* __restrict__ fq,
                                                float* __restrict__ P) {
    const int wid = threadIdx.x >> 6, lane = threadIdx.x & 63;
    const int gw = blockIdx.x * 4 + wid;   // 8192 waves, each does 8 rows
    const float4 f0 = *(const float4*)(fq + lane * 8);
    const float4 f1 = *(const float4*)(fq + lane * 8 + 4);
    float inv[8] = {1.f / f0.x, 1.f / f0.y, 1.f / f0.z, 1.f / f0.w,
                    1.f / f1.x, 1.f / f1.y, 1.f / f1.z, 1.f / f1.w};
    for (int it = 0; it < 8; ++it) {
        const long row = gw + (long)it * 8192;
        const float4* qp = (const float4*)(Q + row * KC + lane * 8);
        float4 q0 = qp[0], q1 = qp[1];
        float n[8];
        n[0] = q0.x * q0.x * inv[0]; n[1] = q0.y * q0.y * inv[1];
        n[2] = q0.z * q0.z * inv[2]; n[3] = q0.w * q0.w * inv[3];
        n[4] = q1.x * q1.x * inv[4]; n[5] = q1.y * q1.y * inv[5];
        n[6] = q1.z * q1.z * inv[6]; n[7] = q1.w * q1.w * inv[7];
        float rs = n[0] + n[1] + n[2] + n[3] + n[4] + n[5] + n[6] + n[7];
        #pragma unroll
        for (int m = 1; m <= 32; m <<= 1) rs += __shfl_xor(rs, m, 64);
        float ir = 1.f / rs;
        float4 o0 = {n[0] * ir, n[1] * ir, n[2] * ir, n[3] * ir};
        float4 o1 = {n[4] * ir, n[5] * ir, n[6] * ir, n[7] * ir};
        float4* pp = (float4*)(P + row * KC + lane * 8);
        pp[0] = o0; pp[1] = o1;
    }
}

extern "C" void kernel_launch(void* const* d_in, const int* in_sizes, int n_in,
                              void* d_out, int out_size, void* d_ws, size_t ws_size,
                              hipStream_t stream) {
    const float* x  = (const float*)d_in[0];
    const float* W  = (const float*)d_in[1];
    const float* b  = (const float*)d_in[2];
    const float* C  = (const float*)d_in[3];

    float* out  = (float*)d_out;
    float* lout = out;                                   // 65536*128
    float* Qout = out + (long)NROWS * DLAT;              // 65536*512
    float* Pout = Qout + (long)NROWS * KC;               // 65536*512

    // workspace layout (~2.44 MB)
    char*  ws      = (char*)d_ws;
    short* Wt      = (short*)ws;                         // 131072 * 2 B
    short* cb      = (short*)(ws + 262144);              // 65536 * 2 B
    float* csq     = (float*)(ws + 262144 + 131072);     // 512 * 4 B
    float* partial = (float*)(ws + 395264);              // 1024*512*4 = 2 MB
    float* fq      = (float*)(ws + 395264 + 2097152);    // 512 * 4 B

    hipLaunchKernelGGL(prep_convert, dim3(768),  dim3(256), 0, stream, W, C, Wt, cb);
    hipLaunchKernelGGL(prep_csq,     dim3(512),  dim3(64),  0, stream, C, csq);
    hipLaunchKernelGGL(gemm_l,       dim3(2048), dim3(256), 0, stream, x, Wt, b, lout);
    hipLaunchKernelGGL(gemm2_q,      dim3(1024), dim3(256), 0, stream, lout, cb, csq, Qout, partial);
    hipLaunchKernelGGL(fq_reduce,    dim3(512),  dim3(256), 0, stream, partial, fq);
    hipLaunchKernelGGL(p_kernel,     dim3(2048), dim3(256), 0, stream, Qout, fq, Pout);
}